// Round 10
// baseline (6840.797 us; speedup 1.0000x reference)
//
#include <hip/hip_runtime.h>
#include <hip/hip_bf16.h>
#include <cstdint>
#include <cstddef>

// output regions (f32 elements)
#define OFF_CE 131072ull                 // c_emb [B,C,E]
#define OFF_MU (131072ull + 16777216ull) // mu
#define OFF_LV (131072ull + 33554432ull) // logvar

using bf16x8 = __attribute__((ext_vector_type(8))) __bf16;
using s16x8  = __attribute__((ext_vector_type(8))) short;
using f32x4  = __attribute__((ext_vector_type(4))) float;

__device__ __forceinline__ unsigned short f2bf(float x) {
  unsigned u = __builtin_bit_cast(unsigned, x);
  return (unsigned short)((u + 0x7FFFu + ((u >> 16) & 1u)) >> 16);
}
__device__ __forceinline__ float bf2f(unsigned short h) {
  unsigned u = ((unsigned)h) << 16;
  return __builtin_bit_cast(float, u);
}
__device__ __forceinline__ void async16(const void* g, void* l) {
  __builtin_amdgcn_global_load_lds(
      (const __attribute__((address_space(1))) void*)g,
      (__attribute__((address_space(3))) void*)l, 16, 0, 0);
}
__device__ __forceinline__ f32x4 nt_load4(const float* p4) {
  return __builtin_nontemporal_load((const f32x4*)p4);
}

// everything the gemm kernel's epilogues need
struct PX {
  const float *b2, *presum, *w2l, *bl1024;
  float *e1024, *pred;
};

// ---- pair-pipelined 64x64 f32 -> bf16 transposed tiles (per 256-thread group) ----
template <int ALIGNED>
__device__ __forceinline__ void tile_tr64_pair(
    const float* __restrict__ srcA, const float* __restrict__ srcB, int stride,
    unsigned short* __restrict__ dstA, unsigned short* __restrict__ dstB,
    int t256, float (*tA)[68], float (*tB)[68]) {
  const int row = t256 >> 4;
  const int col4 = (t256 & 15) << 2;
  f32x4 vA[4], vB[4];
#pragma unroll
  for (int i = 0; i < 4; ++i) {
    const float* q = srcA + (size_t)(row + (i << 4)) * stride + col4;
    if constexpr (ALIGNED) {
      vA[i] = nt_load4(q);
    } else {
      vA[i].x = __builtin_nontemporal_load(q);
      vA[i].y = __builtin_nontemporal_load(q + 1);
      vA[i].z = __builtin_nontemporal_load(q + 2);
      vA[i].w = __builtin_nontemporal_load(q + 3);
    }
  }
#pragma unroll
  for (int i = 0; i < 4; ++i) {
    const float* q = srcB + (size_t)(row + (i << 4)) * stride + col4;
    if constexpr (ALIGNED) {
      vB[i] = nt_load4(q);
    } else {
      vB[i].x = __builtin_nontemporal_load(q);
      vB[i].y = __builtin_nontemporal_load(q + 1);
      vB[i].z = __builtin_nontemporal_load(q + 2);
      vB[i].w = __builtin_nontemporal_load(q + 3);
    }
  }
#pragma unroll
  for (int i = 0; i < 4; ++i) *(f32x4*)&tA[row + (i << 4)][col4] = vA[i];
  __syncthreads();
#pragma unroll
  for (int i = 0; i < 4; ++i) *(f32x4*)&tB[row + (i << 4)][col4] = vB[i];
  const int n = t256 & 63;
#pragma unroll
  for (int pq = 0; pq < 2; ++pq) {
    const int k8 = ((t256 >> 6) << 3) + (pq << 5);
    unsigned short tmp[8];
#pragma unroll
    for (int j = 0; j < 8; ++j) tmp[j] = f2bf(tA[k8 + j][n]);
    *(uint4*)(dstA + (size_t)n * 1024 + k8) = *(uint4*)tmp;
  }
  __syncthreads();
#pragma unroll
  for (int pq = 0; pq < 2; ++pq) {
    const int k8 = ((t256 >> 6) << 3) + (pq << 5);
    unsigned short tmp[8];
#pragma unroll
    for (int j = 0; j < 8; ++j) tmp[j] = f2bf(tB[k8 + j][n]);
    *(uint4*)(dstB + (size_t)n * 1024 + k8) = *(uint4*)tmp;
  }
}

// ---------------- prep1: W1 transpose (4 tiles/block) + x convert + Wl extracts ----------------
__global__ __launch_bounds__(512) void prep1_k(const float* __restrict__ W1,
                                               const float* __restrict__ x,
                                               const float* __restrict__ Wl,
                                               const float* __restrict__ bl,
                                               unsigned short* __restrict__ xb,
                                               unsigned short* __restrict__ W1T,
                                               float* __restrict__ wlastf,
                                               float* __restrict__ blpf,
                                               float* __restrict__ Wlcolf,
                                               float* __restrict__ w2l,
                                               float* __restrict__ bl1024) {
  __shared__ float t[4][64][68];
  const int bid = blockIdx.x;
  const int tid = threadIdx.x;
  if (bid < 4096) {
    const int g = tid >> 8, t256 = tid & 255;
    const int tau0 = (bid << 2) + (g << 1);
    const int c0 = tau0 >> 8, kt0 = (tau0 >> 4) & 15, nt0 = tau0 & 15;
    const int tau1 = tau0 + 1;
    const int c1 = tau1 >> 8, kt1 = (tau1 >> 4) & 15, nt1 = tau1 & 15;
    tile_tr64_pair<1>(
        W1 + ((size_t)c0 << 20) + ((size_t)(kt0 << 6) << 10) + (nt0 << 6),
        W1 + ((size_t)c1 << 20) + ((size_t)(kt1 << 6) << 10) + (nt1 << 6), 1024,
        W1T + ((size_t)c0 << 20) + ((size_t)(nt0 << 6) << 10) + (kt0 << 6),
        W1T + ((size_t)c1 << 20) + ((size_t)(nt1 << 6) << 10) + (kt1 << 6),
        t256, t[g << 1], t[(g << 1) + 1]);
  } else if (bid < 4608) {
    const int idx = (bid - 4096) * 512 + tid;  // < 262144
    f32x4 a = nt_load4(x + (size_t)idx * 8);
    f32x4 b = nt_load4(x + (size_t)idx * 8 + 4);
    unsigned w0 = f2bf(a.x) | ((unsigned)f2bf(a.y) << 16);
    unsigned w1 = f2bf(a.z) | ((unsigned)f2bf(a.w) << 16);
    unsigned w2 = f2bf(b.x) | ((unsigned)f2bf(b.y) << 16);
    unsigned w3 = f2bf(b.z) | ((unsigned)f2bf(b.w) << 16);
    ((uint4*)xb)[idx] = make_uint4(w0, w1, w2, w3);
  } else {
    const int idx = (bid - 4608) * 512 + tid;  // < 65536
    const int c = idx >> 10, j = idx & 1023;
    const float* src = Wl + (size_t)c * 1050625;
    wlastf[idx] = __builtin_nontemporal_load(&src[(size_t)1024 * 1025 + j]);
    blpf[idx]   = bl[(size_t)c * 1025 + j];
    Wlcolf[idx] = __builtin_nontemporal_load(&src[(size_t)j * 1025 + 1024]);
    if (j == 0) {
      w2l[c]    = src[(size_t)1024 * 1025 + 1024];
      bl1024[c] = bl[(size_t)c * 1025 + 1024];
    }
  }
}

// ---------------- wl2: Wl transpose (NT, 4 tiles/block) + Whead + colgemv ----------------
__global__ __launch_bounds__(512) void wl2_k(const float* __restrict__ Wl,
                                             const float* __restrict__ Wmu,
                                             const float* __restrict__ Wlv,
                                             const unsigned short* __restrict__ xb,
                                             const float* __restrict__ Wlcolf,
                                             unsigned short* __restrict__ WlT,
                                             unsigned short* __restrict__ WheadT,
                                             float* __restrict__ whead1024f,
                                             float* __restrict__ presum) {
  __shared__ float t[4][64][68];
  const int bid = blockIdx.x;
  const int tid = threadIdx.x;
  if (bid < 4096) {
    const int g = tid >> 8, t256 = tid & 255;
    const int tau0 = (bid << 2) + (g << 1);
    const int c0 = tau0 >> 8, kt0 = (tau0 >> 4) & 15, nt0 = tau0 & 15;
    const int tau1 = tau0 + 1;
    const int c1 = tau1 >> 8, kt1 = (tau1 >> 4) & 15, nt1 = tau1 & 15;
    tile_tr64_pair<0>(
        Wl + (size_t)c0 * 1050625 + (size_t)(kt0 << 6) * 1025 + (nt0 << 6),
        Wl + (size_t)c1 * 1050625 + (size_t)(kt1 << 6) * 1025 + (nt1 << 6), 1025,
        WlT + ((size_t)c0 << 20) + ((size_t)(nt0 << 6) << 10) + (kt0 << 6),
        WlT + ((size_t)c1 << 20) + ((size_t)(nt1 << 6) << 10) + (kt1 << 6),
        t256, t[g << 1], t[(g << 1) + 1]);
  } else if (bid < 4608) {
    const int we = bid - 4096;
    const int idx = we * 512 + tid;  // < 262144
    const int rr = idx >> 10, k = idx & 1023;
    float v = (rr < 128) ? Wmu[(size_t)k * 128 + rr] : Wlv[(size_t)k * 128 + (rr - 128)];
    WheadT[idx] = f2bf(v);
    if (we == 0 && tid < 256)
      whead1024f[tid] = (tid < 128) ? Wmu[131072 + tid] : Wlv[131072 + (tid - 128)];
  } else {
    const int b = bid - 4608;  // < 2048
    const int w = tid >> 6, lane = tid & 63;
    const unsigned short* xr = xb + ((size_t)b << 10) + lane * 16;
    s16x8 xv0 = *(const s16x8*)xr;
    s16x8 xv1 = *(const s16x8*)(xr + 8);
    float xf[16];
#pragma unroll
    for (int i = 0; i < 8; ++i) {
      xf[i] = bf2f((unsigned short)xv0[i]);
      xf[8 + i] = bf2f((unsigned short)xv1[i]);
    }
#pragma unroll
    for (int q = 0; q < 8; ++q) {
      const int c = (q << 3) + w;
      const float* wr = Wlcolf + (c << 10) + lane * 16;
      float s = 0.f;
#pragma unroll
      for (int q4 = 0; q4 < 4; ++q4) {
        f32x4 wv = *(const f32x4*)(wr + q4 * 4);
        s += xf[q4 * 4 + 0] * wv.x + xf[q4 * 4 + 1] * wv.y +
             xf[q4 * 4 + 2] * wv.z + xf[q4 * 4 + 3] * wv.w;
      }
#pragma unroll
      for (int off = 32; off; off >>= 1) s += __shfl_xor(s, off);
      if (lane == 0) presum[(c << 11) + b] = s;
    }
  }
}

// ---------------- 256x256 MFMA GEMM, BK=32, 64 KB LDS -> 2 blocks/CU ----------------
// MODE 0: h-tile + fused scorer partials -> ofl=spart[4][C][B]
// MODE 1: emb = relu(acc + cp*wlast + blp), in-epilogue sigmoid -> obf [C][B][1024]
// MODE 2: mu/lv/ce = acc + bias + e1024*whead1024 -> d_out

#define BAR() __builtin_amdgcn_s_barrier()
#define LGKM0() do { asm volatile("s_waitcnt lgkmcnt(0)" ::: "memory"); \
                     __builtin_amdgcn_sched_barrier(0); } while (0)
#define VM2() asm volatile("s_waitcnt vmcnt(2)" ::: "memory")
#define VM0() asm volatile("s_waitcnt vmcnt(0)" ::: "memory")

// one async16 per thread per half-tile (128 rows x 32 k = 8 KB = 512 x 16 B)
#define STAGEA(h, tt, bidx) \
  async16(Asrc + ((size_t)(h) * 128) * K + (size_t)(tt) * 32, &sA[bidx][(h) * 4096 + chnk])
#define STAGEB(h, tt, bidx) \
  async16(Bsrc + ((size_t)(h) * 128) * K + (size_t)(tt) * 32, &sB[bidx][(h) * 4096 + chnk])

#define LOADA(mh, bidx) do { _Pragma("unroll") for (int i_ = 0; i_ < 4; ++i_) { \
  const int r_ = (mh) * 128 + wm64 + i_ * 16 + l15; \
  a[i_] = *(const bf16x8*)&sA[bidx][(r_ << 5) + ccx]; } } while (0)

#define LOADB(nh, bb, bidx) do { _Pragma("unroll") for (int j_ = 0; j_ < 2; ++j_) { \
  const int r_ = (nh) * 128 + wn32 + j_ * 16 + l15; \
  bb[j_] = *(const bf16x8*)&sB[bidx][(r_ << 5) + ccx]; } } while (0)

#define MMAQ(mh, nh, bb) do { _Pragma("unroll") for (int i_ = 0; i_ < 4; ++i_) \
  _Pragma("unroll") for (int j_ = 0; j_ < 2; ++j_) \
    acc[(mh)*4+i_][(nh)*2+j_] = __builtin_amdgcn_mfma_f32_16x16x32_bf16( \
        a[i_], bb[j_], acc[(mh)*4+i_][(nh)*2+j_], 0, 0, 0); } while (0)

// one K-tile (BK=32), 4 phases, compile-time LDS buffer selection
#define KSTEP(t_, cb_, nb_) do { \
    LOADA(0, cb_); LOADB(0, b0, cb_); STAGEA(0, (t_) + 1, nb_); \
    BAR(); LGKM0(); \
    __builtin_amdgcn_s_setprio(1); MMAQ(0, 0, b0); __builtin_amdgcn_s_setprio(0); \
    VM2(); BAR(); \
    LOADB(1, b1, cb_); STAGEB(0, (t_) + 1, nb_); \
    BAR(); LGKM0(); \
    __builtin_amdgcn_s_setprio(1); MMAQ(0, 1, b1); __builtin_amdgcn_s_setprio(0); \
    VM2(); BAR(); \
    LOADA(1, cb_); STAGEB(1, (t_) + 1, nb_); \
    BAR(); LGKM0(); \
    __builtin_amdgcn_s_setprio(1); MMAQ(1, 1, b1); __builtin_amdgcn_s_setprio(0); \
    BAR(); \
    STAGEA(1, (t_) + 1, nb_); \
    BAR(); \
    __builtin_amdgcn_s_setprio(1); MMAQ(1, 0, b0); __builtin_amdgcn_s_setprio(0); \
    VM2(); BAR(); \
  } while (0)

template <int MODE, int K>
__global__ __launch_bounds__(512, 4) void gemm8p_k(
    const unsigned short* __restrict__ A, const unsigned short* __restrict__ BT,
    const float* __restrict__ e0, const float* __restrict__ e1,
    const float* __restrict__ e2, const float* __restrict__ e3,
    unsigned short* __restrict__ obf, float* __restrict__ ofl, PX p) {
  __shared__ unsigned short sA[2][8192];   // [2 dbuf][256 rows x 32 k]
  __shared__ unsigned short sB[2][8192];

  constexpr int GX = (MODE == 2) ? 1 : 4;
  constexpr int GY = (MODE == 2) ? 512 : 8;
  constexpr int NWG = GX * GY * ((MODE == 2) ? 1 : 64);

  const int tid = threadIdx.x;
  const int lane = tid & 63;
  const int wid = tid >> 6;
  const int wm = wid >> 2, wn = wid & 3;
  const int l15 = lane & 15, l4 = lane >> 4;
  const int wm64 = wm << 6, wn32 = wn << 5;

  // T1: bijective XCD swizzle (NWG % 8 == 0 for all modes)
  const int rbid = blockIdx.x + GX * (blockIdx.y + GY * blockIdx.z);
  const int bid = (rbid & 7) * (NWG >> 3) + (rbid >> 3);
  const int bx = bid % GX;
  const int by = (bid / GX) % GY;
  const int c = bid / (GX * GY);

  const int n0 = bx << 8;
  const int m0 = by << 8;

  const unsigned short* Ab = A;
  const unsigned short* Bb;
  if constexpr (MODE == 2) Bb = BT;
  else                     Bb = BT + ((size_t)c << 20);

  // staging geometry (BK=32): slot=tid, row=tid>>2, stored chunk tid&3 holds
  // source chunk (tid&3)^(row&3); LDS dest linear at tid*16B.
  const int rloc = tid >> 2;
  const int csrc = (((tid & 3) ^ ((tid >> 2) & 3)) << 3);
  const int chnk = tid << 3;  // ushort offset = tid*16B
  const unsigned short* Asrc = Ab + (size_t)(m0 + rloc) * K + csrc;
  const unsigned short* Bsrc = Bb + (size_t)(n0 + rloc) * K + csrc;

  // swizzled ds_read chunk offset: lane reads row r (r&3 == l15&3), chunk l4
  const int ccx = ((l4 ^ (l15 & 3)) << 3);

  f32x4 acc[8][4];
#pragma unroll
  for (int i = 0; i < 8; ++i)
#pragma unroll
    for (int j = 0; j < 4; ++j) acc[i][j] = (f32x4)(0.f);

  bf16x8 a[4], b0[2], b1[2];

  // K = 1024 -> 32 K-tiles; 31 pipelined + 1 drained final (buffer 1)
  static_assert(K == 1024, "schedule assumes 32 K-tiles");

  // prologue: stage tile 0, drain, barrier
  STAGEA(0, 0, 0); STAGEB(0, 0, 0); STAGEB(1, 0, 0); STAGEA(1, 0, 0);
  VM0();
  BAR();

#pragma unroll 1
  for (int tt = 0; tt < 15; ++tt) {
    const int t0 = tt << 1;
    KSTEP(t0, 0, 1);
    KSTEP(t0 + 1, 1, 0);
  }
  KSTEP(30, 0, 1);

  // ---- final tile t=31 in buffer 1 (race-safe: full drain; no further staging) ----
  {
    VM0();
    BAR();
    LOADA(0, 1);
    LOADB(0, b0, 1);
    LGKM0();
    __builtin_amdgcn_s_setprio(1);
    MMAQ(0, 0, b0);
    __builtin_amdgcn_s_setprio(0);
    LOADB(1, b1, 1);
    LGKM0();
    __builtin_amdgcn_s_setprio(1);
    MMAQ(0, 1, b1);
    __builtin_amdgcn_s_setprio(0);
    LOADA(1, 1);
    LGKM0();
    __builtin_amdgcn_s_setprio(1);
    MMAQ(1, 1, b1);
    MMAQ(1, 0, b0);
    __builtin_amdgcn_s_setprio(0);
  }

  // ---- epilogue ----
  int coln[2][2];
#pragma unroll
  for (int nh = 0; nh < 2; ++nh)
#pragma unroll
    for (int j = 0; j < 2; ++j) coln[nh][j] = n0 + nh * 128 + wn32 + j * 16 + l15;

  if constexpr (MODE == 0) {
    // fused scorer: s_partial[row] = sum over this block's 256 cols of relu(h)*w2
    float bias[2][2], w2v[2][2];
#pragma unroll
    for (int nh = 0; nh < 2; ++nh)
#pragma unroll
      for (int j = 0; j < 2; ++j) {
        bias[nh][j] = e0[(c << 10) + coln[nh][j]];
        w2v[nh][j]  = e1[(c << 10) + coln[nh][j]];
      }
    float* partL = (float*)&sA[0][0];  // final tile used buf 1 -> sA[0] free (4 KB < 16 KB)
#pragma unroll
    for (int mh = 0; mh < 2; ++mh)
#pragma unroll
      for (int i = 0; i < 4; ++i)
#pragma unroll
        for (int rr = 0; rr < 4; ++rr) {
          float s = 0.f;
#pragma unroll
          for (int nh = 0; nh < 2; ++nh)
#pragma unroll
            for (int j = 0; j < 2; ++j) {
              float v = fmaxf(acc[mh * 4 + i][nh * 2 + j][rr] + bias[nh][j], 0.f);
              s += v * w2v[nh][j];
            }
          s += __shfl_xor(s, 1); s += __shfl_xor(s, 2);
          s += __shfl_xor(s, 4); s += __shfl_xor(s, 8);
          if (l15 == 0) partL[wid * 128 + mh * 64 + i * 16 + (l4 << 2) + rr] = s;
        }
    __syncthreads();
    if (tid < 256) {
      const int r = tid;
      const int mh_ = r >> 7, wmr = (r >> 6) & 1, low = r & 63;
      float s2 = 0.f;
#pragma unroll
      for (int wn2 = 0; wn2 < 4; ++wn2) s2 += partL[(wmr * 4 + wn2) * 128 + mh_ * 64 + low];
      ofl[(((size_t)(bx << 6) + c) << 11) + m0 + r] = s2;
    }
  } else if constexpr (MODE == 1) {
    // in-epilogue sigmoid: cp for this block's 256 rows (e2 = spart)
    float* cpL = (float*)&sA[0][0];
    if (tid < 256) {
      const int b = m0 + tid;
      float s = p.b2[c];
#pragma unroll
      for (int q = 0; q < 4; ++q) s += e2[(((size_t)(q << 6) + c) << 11) + b];
      float pv = 1.f / (1.f + expf(-s));
      cpL[tid] = pv;
      if (bx == 0) {
        p.pred[((size_t)b << 6) + c] = pv;
        p.e1024[(c << 11) + b] =
            fmaxf(p.presum[(c << 11) + b] + pv * p.w2l[c] + p.bl1024[c], 0.f);
      }
    }
    __syncthreads();
    float wl4[2][2], bb4[2][2];
#pragma unroll
    for (int nh = 0; nh < 2; ++nh)
#pragma unroll
      for (int j = 0; j < 2; ++j) {
        wl4[nh][j] = e0[(c << 10) + coln[nh][j]];
        bb4[nh][j] = e1[(c << 10) + coln[nh][j]];
      }
#pragma unroll
    for (int mh = 0; mh < 2; ++mh)
#pragma unroll
      for (int i = 0; i < 4; ++i)
#pragma unroll
        for (int rr = 0; rr < 4; ++rr) {
          const int rl = mh * 128 + wm64 + i * 16 + (l4 << 2) + rr;
          const int row = m0 + rl;  // = b
          const float cp = cpL[rl];
          unsigned short* orow = obf + (((size_t)(c << 11) + row) << 10);
#pragma unroll
          for (int nh = 0; nh < 2; ++nh)
#pragma unroll
            for (int j = 0; j < 2; ++j) {
              float v = acc[mh * 4 + i][nh * 2 + j][rr] + cp * wl4[nh][j] + bb4[nh][j];
              orow[coln[nh][j]] = f2bf(fmaxf(v, 0.f));
            }
        }
  } else {
    float bias[2][2], wh[2][2];
#pragma unroll
    for (int nh = 0; nh < 2; ++nh)
#pragma unroll
      for (int j = 0; j < 2; ++j) {
        bias[nh][j] = (nh == 0) ? e0[coln[0][j]] : e1[coln[1][j] - 128];
        wh[nh][j]   = e3[coln[nh][j]];
      }
#pragma unroll
    for (int mh = 0; mh < 2; ++mh)
#pragma unroll
      for (int i = 0; i < 4; ++i)
#pragma unroll
        for (int rr = 0; rr < 4; ++rr) {
          const int rid = m0 + mh * 128 + wm64 + i * 16 + (l4 << 2) + rr;  // c*B + b
          const int cc = rid >> 11, b = rid & 2047;
          const float ev = e2[rid];  // e1024[c][b]
          const size_t ib = (((size_t)b << 6) + cc) << 7;
#pragma unroll
          for (int j = 0; j < 2; ++j) {  // nh=0 -> mu & ce
            float v = acc[mh * 4 + i][j][rr] + bias[0][j] + ev * wh[0][j];
            ofl[OFF_MU + ib + coln[0][j]] = v;
            ofl[OFF_CE + ib + coln[0][j]] = v;
          }
#pragma unroll
          for (int j = 0; j < 2; ++j) {  // nh=1 -> logvar
            float v = acc[mh * 4 + i][2 + j][rr] + bias[1][j] + ev * wh[1][j];
            ofl[OFF_LV + ib + (coln[1][j] - 128)] = v;
          }
        }
  }
}

// ---------------- launcher ----------------

extern "C" void kernel_launch(void* const* d_in, const int* in_sizes, int n_in,
                              void* d_out, int out_size, void* d_ws, size_t ws_size,
                              hipStream_t stream) {
  const float* x   = (const float*)d_in[0];
  const float* W1  = (const float*)d_in[2];
  const float* b1  = (const float*)d_in[3];
  const float* w2  = (const float*)d_in[4];
  const float* b2  = (const float*)d_in[5];
  const float* Wl  = (const float*)d_in[6];
  const float* bl  = (const float*)d_in[7];
  const float* Wmu = (const float*)d_in[8];
  const float* bmu = (const float*)d_in[9];
  const float* Wlv = (const float*)d_in[10];
  const float* blv = (const float*)d_in[11];
  float* out = (float*)d_out;

  char* ws = (char*)d_ws;
  size_t off = 0;
  auto take = [&](size_t bytes) { char* r = ws + off; off += bytes; return r; };
  unsigned short* xb     = (unsigned short*)take(4194304);
  unsigned short* W1T    = (unsigned short*)take(134217728);
  unsigned short* WlT    = (unsigned short*)take(134217728);
  float* wlastf          = (float*)take(262144);
  float* blpf            = (float*)take(262144);
  float* Wlcolf          = (float*)take(262144);
  float* w2l             = (float*)take(512);
  float* bl1024          = (float*)take(512);
  unsigned short* WheadT = (unsigned short*)take(524288);
  float* whead1024f      = (float*)take(1024);
  float* presum          = (float*)take(524288);
  float* spart           = (float*)take(2097152);
  float* e1024f          = (float*)take(524288);
  unsigned short* emb    = (unsigned short*)take(268435456);
  // total = 545,523,712 bytes (fits: rounds 4/6/8/9 ran this footprint)

  PX p;
  p.b2 = b2; p.presum = presum; p.w2l = w2l; p.bl1024 = bl1024;
  p.e1024 = e1024f; p.pred = out;

  prep1_k<<<4736, 512, 0, stream>>>(W1, x, Wl, bl, xb, W1T, wlastf, blpf, Wlcolf, w2l, bl1024);
  gemm8p_k<0, 1024><<<dim3(4, 8, 64), 512, 0, stream>>>(xb, W1T, b1, w2, nullptr, nullptr,
                                                        nullptr, spart, p);
  wl2_k<<<6656, 512, 0, stream>>>(Wl, Wmu, Wlv, xb, Wlcolf, WlT, WheadT, whead1024f, presum);
  gemm8p_k<1, 1024><<<dim3(4, 8, 64), 512, 0, stream>>>(xb, WlT, wlastf, blpf, spart, nullptr,
                                                        emb, nullptr, p);
  gemm8p_k<2, 1024><<<dim3(1, 512, 1), 512, 0, stream>>>(emb, WheadT, bmu, blv, e1024f,
                                                         whead1024f, nullptr, out, p);
}

// Round 11
// 961.904 us; speedup vs baseline: 7.1117x; 7.1117x over previous
//
#include <hip/hip_runtime.h>
#include <hip/hip_bf16.h>
#include <cstdint>
#include <cstddef>

// output regions (f32 elements)
#define OFF_CE 131072ull                 // c_emb [B,C,E]
#define OFF_MU (131072ull + 16777216ull) // mu
#define OFF_LV (131072ull + 33554432ull) // logvar

using bf16x8 = __attribute__((ext_vector_type(8))) __bf16;
using s16x8  = __attribute__((ext_vector_type(8))) short;
using f32x4  = __attribute__((ext_vector_type(4))) float;

__device__ __forceinline__ unsigned short f2bf(float x) {
  unsigned u = __builtin_bit_cast(unsigned, x);
  return (unsigned short)((u + 0x7FFFu + ((u >> 16) & 1u)) >> 16);
}
__device__ __forceinline__ float bf2f(unsigned short h) {
  unsigned u = ((unsigned)h) << 16;
  return __builtin_bit_cast(float, u);
}
__device__ __forceinline__ void async16(const void* g, void* l) {
  __builtin_amdgcn_global_load_lds(
      (const __attribute__((address_space(1))) void*)g,
      (__attribute__((address_space(3))) void*)l, 16, 0, 0);
}
__device__ __forceinline__ f32x4 nt_load4(const float* p4) {
  return __builtin_nontemporal_load((const f32x4*)p4);
}

// everything the gemm kernel's epilogues + tail blocks need
struct PX {
  const float *Wl, *Wmu, *Wlv, *b2, *w2l, *bl1024, *Wlcolf;
  const unsigned short *xb;
  unsigned short *WlT, *WheadT;
  float *whead1024f, *presum, *e1024, *pred;
};

// ---- pair-pipelined 64x64 f32 -> bf16 transposed tiles (per 256-thread group) ----
// Issues all 8 NT loads up front (tile B's HBM latency hides under tile A's LDS work).
// Block-wide __syncthreads: all 256-groups in the block follow the identical sequence.
template <int ALIGNED>
__device__ __forceinline__ void tile_tr64_pair(
    const float* __restrict__ srcA, const float* __restrict__ srcB, int stride,
    unsigned short* __restrict__ dstA, unsigned short* __restrict__ dstB,
    int t256, float (*tA)[68], float (*tB)[68]) {
  const int row = t256 >> 4;
  const int col4 = (t256 & 15) << 2;
  f32x4 vA[4], vB[4];
#pragma unroll
  for (int i = 0; i < 4; ++i) {
    const float* q = srcA + (size_t)(row + (i << 4)) * stride + col4;
    if constexpr (ALIGNED) {
      vA[i] = nt_load4(q);
    } else {
      vA[i].x = __builtin_nontemporal_load(q);
      vA[i].y = __builtin_nontemporal_load(q + 1);
      vA[i].z = __builtin_nontemporal_load(q + 2);
      vA[i].w = __builtin_nontemporal_load(q + 3);
    }
  }
#pragma unroll
  for (int i = 0; i < 4; ++i) {
    const float* q = srcB + (size_t)(row + (i << 4)) * stride + col4;
    if constexpr (ALIGNED) {
      vB[i] = nt_load4(q);
    } else {
      vB[i].x = __builtin_nontemporal_load(q);
      vB[i].y = __builtin_nontemporal_load(q + 1);
      vB[i].z = __builtin_nontemporal_load(q + 2);
      vB[i].w = __builtin_nontemporal_load(q + 3);
    }
  }
#pragma unroll
  for (int i = 0; i < 4; ++i) *(f32x4*)&tA[row + (i << 4)][col4] = vA[i];
  __syncthreads();
#pragma unroll
  for (int i = 0; i < 4; ++i) *(f32x4*)&tB[row + (i << 4)][col4] = vB[i];
  const int n = t256 & 63;
#pragma unroll
  for (int pq = 0; pq < 2; ++pq) {
    const int k8 = ((t256 >> 6) << 3) + (pq << 5);
    unsigned short tmp[8];
#pragma unroll
    for (int j = 0; j < 8; ++j) tmp[j] = f2bf(tA[k8 + j][n]);
    *(uint4*)(dstA + (size_t)n * 1024 + k8) = *(uint4*)tmp;
  }
  __syncthreads();
#pragma unroll
  for (int pq = 0; pq < 2; ++pq) {
    const int k8 = ((t256 >> 6) << 3) + (pq << 5);
    unsigned short tmp[8];
#pragma unroll
    for (int j = 0; j < 8; ++j) tmp[j] = f2bf(tB[k8 + j][n]);
    *(uint4*)(dstB + (size_t)n * 1024 + k8) = *(uint4*)tmp;
  }
}

// ---------------- prep1: W1 transpose (4 tiles/block) + x convert + Wl extracts ----------------
// NT reads: inputs are streamed once; outputs (W1T, xb) stay L3-resident for gemm1.
__global__ __launch_bounds__(512) void prep1_k(const float* __restrict__ W1,
                                               const float* __restrict__ x,
                                               const float* __restrict__ Wl,
                                               const float* __restrict__ bl,
                                               unsigned short* __restrict__ xb,
                                               unsigned short* __restrict__ W1T,
                                               float* __restrict__ wlastf,
                                               float* __restrict__ blpf,
                                               float* __restrict__ Wlcolf,
                                               float* __restrict__ w2l,
                                               float* __restrict__ bl1024) {
  __shared__ float t[4][64][68];
  const int bid = blockIdx.x;
  const int tid = threadIdx.x;
  if (bid < 4096) {
    const int g = tid >> 8, t256 = tid & 255;
    const int tau0 = (bid << 2) + (g << 1);
    const int c0 = tau0 >> 8, kt0 = (tau0 >> 4) & 15, nt0 = tau0 & 15;
    const int tau1 = tau0 + 1;
    const int c1 = tau1 >> 8, kt1 = (tau1 >> 4) & 15, nt1 = tau1 & 15;
    tile_tr64_pair<1>(
        W1 + ((size_t)c0 << 20) + ((size_t)(kt0 << 6) << 10) + (nt0 << 6),
        W1 + ((size_t)c1 << 20) + ((size_t)(kt1 << 6) << 10) + (nt1 << 6), 1024,
        W1T + ((size_t)c0 << 20) + ((size_t)(nt0 << 6) << 10) + (kt0 << 6),
        W1T + ((size_t)c1 << 20) + ((size_t)(nt1 << 6) << 10) + (kt1 << 6),
        t256, t[g << 1], t[(g << 1) + 1]);
  } else if (bid < 4608) {
    const int idx = (bid - 4096) * 512 + tid;  // < 262144
    f32x4 a = nt_load4(x + (size_t)idx * 8);
    f32x4 b = nt_load4(x + (size_t)idx * 8 + 4);
    unsigned w0 = f2bf(a.x) | ((unsigned)f2bf(a.y) << 16);
    unsigned w1 = f2bf(a.z) | ((unsigned)f2bf(a.w) << 16);
    unsigned w2 = f2bf(b.x) | ((unsigned)f2bf(b.y) << 16);
    unsigned w3 = f2bf(b.z) | ((unsigned)f2bf(b.w) << 16);
    ((uint4*)xb)[idx] = make_uint4(w0, w1, w2, w3);
  } else {
    const int idx = (bid - 4608) * 512 + tid;  // < 65536
    const int c = idx >> 10, j = idx & 1023;
    const float* src = Wl + (size_t)c * 1050625;
    wlastf[idx] = __builtin_nontemporal_load(&src[(size_t)1024 * 1025 + j]);
    blpf[idx]   = bl[(size_t)c * 1025 + j];
    Wlcolf[idx] = __builtin_nontemporal_load(&src[(size_t)j * 1025 + 1024]);
    if (j == 0) {
      w2l[c]    = src[(size_t)1024 * 1025 + 1024];
      bl1024[c] = bl[(size_t)c * 1025 + 1024];
    }
  }
}

// ---------------- tail work hidden in gemm1's dispatch ----------------
// e < 4096: Wl transpose, 4 tiles/block pair-pipelined (NT reads keep gemm1's
// panels cached; WlT lands in L3 right before gemm2 -> warm staging);
// [4096,4608): Whead; [4608,6656): colgemv.
__device__ void tail_work(int e, int tid, char* lds, const PX& p) {
  if (e < 4096) {
    const int g = tid >> 8, t256 = tid & 255;
    const int tau0 = (e << 2) + (g << 1);  // tiles tau0, tau0+1 (of 16384)
    const int c0 = tau0 >> 8, kt0 = (tau0 >> 4) & 15, nt0 = tau0 & 15;
    const int tau1 = tau0 + 1;
    const int c1 = tau1 >> 8, kt1 = (tau1 >> 4) & 15, nt1 = tau1 & 15;
    tile_tr64_pair<0>(
        p.Wl + (size_t)c0 * 1050625 + (size_t)(kt0 << 6) * 1025 + (nt0 << 6),
        p.Wl + (size_t)c1 * 1050625 + (size_t)(kt1 << 6) * 1025 + (nt1 << 6), 1025,
        p.WlT + ((size_t)c0 << 20) + ((size_t)(nt0 << 6) << 10) + (kt0 << 6),
        p.WlT + ((size_t)c1 << 20) + ((size_t)(nt1 << 6) << 10) + (kt1 << 6),
        t256, (float(*)[68])(lds + g * 34816), (float(*)[68])(lds + g * 34816 + 17408));
    return;
  }
  if (e < 4608) {  // Whead convert
    const int we = e - 4096;
    const int idx = we * 512 + tid;  // < 262144
    const int rr = idx >> 10, k = idx & 1023;
    float v = (rr < 128) ? p.Wmu[(size_t)k * 128 + rr] : p.Wlv[(size_t)k * 128 + (rr - 128)];
    p.WheadT[idx] = f2bf(v);
    if (we == 0 && tid < 256)
      p.whead1024f[tid] = (tid < 128) ? p.Wmu[131072 + tid] : p.Wlv[131072 + (tid - 128)];
    return;
  }
  // colgemv: presum[c][b] = x_b . Wlcol[c]
  const int b = e - 4608;  // < 2048
  const int w = tid >> 6, lane = tid & 63;
  const unsigned short* xr = p.xb + ((size_t)b << 10) + lane * 16;
  s16x8 xv0 = *(const s16x8*)xr;
  s16x8 xv1 = *(const s16x8*)(xr + 8);
  float xf[16];
#pragma unroll
  for (int i = 0; i < 8; ++i) {
    xf[i] = bf2f((unsigned short)xv0[i]);
    xf[8 + i] = bf2f((unsigned short)xv1[i]);
  }
#pragma unroll
  for (int q = 0; q < 8; ++q) {
    const int c = (q << 3) + w;
    const float* wr = p.Wlcolf + (c << 10) + lane * 16;
    float s = 0.f;
#pragma unroll
    for (int q4 = 0; q4 < 4; ++q4) {
      f32x4 wv = *(const f32x4*)(wr + q4 * 4);
      s += xf[q4 * 4 + 0] * wv.x + xf[q4 * 4 + 1] * wv.y +
           xf[q4 * 4 + 2] * wv.z + xf[q4 * 4 + 3] * wv.w;
    }
#pragma unroll
    for (int off = 32; off; off >>= 1) s += __shfl_xor(s, off);
    if (lane == 0) p.presum[(c << 11) + b] = s;
  }
}

// ---------------- 256x256 8-phase MFMA GEMM (T1+T2+T3+T4+T5), BK=64 ----------------
// MODE 0: h-tile + fused scorer partials -> ofl=spart[4][C][B]  (+6656 tail blocks)
// MODE 1: emb = relu(acc + cp*wlast + blp), in-epilogue sigmoid -> obf [C][B][1024]
// MODE 2: mu/lv/ce = acc + bias + e1024*whead1024 -> d_out

#define BAR() __builtin_amdgcn_s_barrier()
#define LGKM0() do { asm volatile("s_waitcnt lgkmcnt(0)" ::: "memory"); \
                     __builtin_amdgcn_sched_barrier(0); } while (0)
#define VM4() asm volatile("s_waitcnt vmcnt(4)" ::: "memory")
#define VM0() asm volatile("s_waitcnt vmcnt(0)" ::: "memory")

#define STAGEA(h, tt, bidx) do { _Pragma("unroll") for (int q_ = 0; q_ < 2; ++q_) \
  async16(Asrc[q_] + ((size_t)(h) * 128) * K + (size_t)(tt) * 64, \
          &sA[bidx][(h) * 8192 + chnk[q_]]); } while (0)
#define STAGEB(h, tt, bidx) do { _Pragma("unroll") for (int q_ = 0; q_ < 2; ++q_) \
  async16(Bsrc[q_] + ((size_t)(h) * 128) * K + (size_t)(tt) * 64, \
          &sB[bidx][(h) * 8192 + chnk[q_]]); } while (0)

#define LOADA(mh, bidx) do { _Pragma("unroll") for (int i_ = 0; i_ < 4; ++i_) { \
  const int ro_ = ((mh) * 128 + wm64 + i_ * 16 + l15) << 6; \
  a[i_][0] = *(const bf16x8*)&sA[bidx][ro_ + ccx0]; \
  a[i_][1] = *(const bf16x8*)&sA[bidx][ro_ + ccx1]; } } while (0)

#define LOADB(nh, bb, bidx) do { _Pragma("unroll") for (int j_ = 0; j_ < 2; ++j_) { \
  const int ro_ = ((nh) * 128 + wn32 + j_ * 16 + l15) << 6; \
  bb[j_][0] = *(const bf16x8*)&sB[bidx][ro_ + ccx0]; \
  bb[j_][1] = *(const bf16x8*)&sB[bidx][ro_ + ccx1]; } } while (0)

#define MMAQ(mh, nh, bb) do { _Pragma("unroll") for (int i_ = 0; i_ < 4; ++i_) \
  _Pragma("unroll") for (int j_ = 0; j_ < 2; ++j_) { \
    acc[(mh)*4+i_][(nh)*2+j_] = __builtin_amdgcn_mfma_f32_16x16x32_bf16( \
        a[i_][0], bb[j_][0], acc[(mh)*4+i_][(nh)*2+j_], 0, 0, 0); \
    acc[(mh)*4+i_][(nh)*2+j_] = __builtin_amdgcn_mfma_f32_16x16x32_bf16( \
        a[i_][1], bb[j_][1], acc[(mh)*4+i_][(nh)*2+j_], 0, 0, 0); \
  } } while (0)

// one full K-tile (4 phases) with compile-time LDS buffer selection
#define KSTEP(t_, cb_, nb_) do { \
    LOADA(0, cb_); LOADB(0, b0, cb_); STAGEA(0, (t_) + 1, nb_); \
    BAR(); LGKM0(); \
    __builtin_amdgcn_s_setprio(1); MMAQ(0, 0, b0); __builtin_amdgcn_s_setprio(0); \
    VM4(); BAR(); \
    LOADB(1, b1, cb_); STAGEB(0, (t_) + 1, nb_); \
    BAR(); LGKM0(); \
    __builtin_amdgcn_s_setprio(1); MMAQ(0, 1, b1); __builtin_amdgcn_s_setprio(0); \
    VM4(); BAR(); \
    LOADA(1, cb_); STAGEB(1, (t_) + 1, nb_); \
    BAR(); LGKM0(); \
    __builtin_amdgcn_s_setprio(1); MMAQ(1, 1, b1); __builtin_amdgcn_s_setprio(0); \
    BAR(); \
    STAGEA(1, (t_) + 1, nb_); \
    BAR(); \
    __builtin_amdgcn_s_setprio(1); MMAQ(1, 0, b0); __builtin_amdgcn_s_setprio(0); \
    VM4(); BAR(); \
  } while (0)

template <int MODE, int K>
__global__ __launch_bounds__(512, 2) void gemm8p_k(
    const unsigned short* __restrict__ A, const unsigned short* __restrict__ BT,
    const float* __restrict__ e0, const float* __restrict__ e1,
    const float* __restrict__ e2, const float* __restrict__ e3,
    unsigned short* __restrict__ obf, float* __restrict__ ofl, PX p) {
  __shared__ unsigned short sA[2][16384];
  __shared__ unsigned short sB[2][16384];

  constexpr int GX = (MODE == 2) ? 1 : 4;
  constexpr int GY = (MODE == 2) ? 512 : 8;
  constexpr int NWG = GX * GY * ((MODE == 2) ? 1 : 64);

  const int tid = threadIdx.x;

  int rbid;
  if constexpr (MODE == 0) {
    const int bidR = blockIdx.x;
    if (bidR >= 2048) { tail_work(bidR - 2048, tid, (char*)&sA[0][0], p); return; }
    rbid = bidR;
  } else {
    rbid = blockIdx.x + GX * (blockIdx.y + GY * blockIdx.z);
  }

  const int lane = tid & 63;
  const int wid = tid >> 6;
  const int wm = wid >> 2, wn = wid & 3;
  const int l15 = lane & 15, l4 = lane >> 4;
  const int wm64 = wm << 6, wn32 = wn << 5;

  // T1: bijective XCD swizzle (NWG % 8 == 0 for all modes)
  const int bid = (rbid & 7) * (NWG >> 3) + (rbid >> 3);
  const int bx = bid % GX;
  const int by = (bid / GX) % GY;
  const int c = bid / (GX * GY);

  const int n0 = bx << 8;
  const int m0 = by << 8;

  const unsigned short* Ab = A;
  const unsigned short* Bb;
  if constexpr (MODE == 2) Bb = BT;
  else                     Bb = BT + ((size_t)c << 20);

  // staging geometry: slot s holds source 16B-chunk (row=s>>3, cc=(s&7)^(row&7))
  int rloc[2], csrc[2], chnk[2];
  const unsigned short* Asrc[2];
  const unsigned short* Bsrc[2];
#pragma unroll
  for (int q = 0; q < 2; ++q) {
    const int s = ((wid << 1) + q) * 64 + lane;
    rloc[q] = s >> 3;
    csrc[q] = ((s & 7) ^ ((s >> 3) & 7)) << 3;
    chnk[q] = ((wid << 1) + q) << 9;
    Asrc[q] = Ab + (size_t)(m0 + rloc[q]) * K + csrc[q];
    Bsrc[q] = Bb + (size_t)(n0 + rloc[q]) * K + csrc[q];
  }

  // swizzled ds_read col-chunk offsets (in ushorts)
  const int xorv = l15 & 7;
  const int ccx0 = (l4 ^ xorv) << 3;
  const int ccx1 = ((4 + l4) ^ xorv) << 3;

  f32x4 acc[8][4];
#pragma unroll
  for (int i = 0; i < 8; ++i)
#pragma unroll
    for (int j = 0; j < 4; ++j) acc[i][j] = (f32x4)(0.f);

  bf16x8 a[4][2], b0[2][2], b1[2][2];

  // K = 1024 -> 16 K-tiles; 15 pipelined + 1 drained final
  static_assert(K == 1024, "schedule assumes 16 K-tiles");

  // prologue: stage tile 0, drain, barrier
  STAGEA(0, 0, 0); STAGEB(0, 0, 0); STAGEB(1, 0, 0); STAGEA(1, 0, 0);
  VM0();
  BAR();

#pragma unroll 1
  for (int tt = 0; tt < 7; ++tt) {
    const int t0 = tt << 1;
    KSTEP(t0, 0, 1);
    KSTEP(t0 + 1, 1, 0);
  }
  KSTEP(14, 0, 1);

  // ---- final tile t=15 in buffer 1 (race-safe: full drain; no further staging) ----
  {
    VM0();
    BAR();
    LOADA(0, 1);
    LOADB(0, b0, 1);
    LGKM0();
    __builtin_amdgcn_s_setprio(1);
    MMAQ(0, 0, b0);
    __builtin_amdgcn_s_setprio(0);
    LOADB(1, b1, 1);
    LGKM0();
    __builtin_amdgcn_s_setprio(1);
    MMAQ(0, 1, b1);
    __builtin_amdgcn_s_setprio(0);
    LOADA(1, 1);
    LGKM0();
    __builtin_amdgcn_s_setprio(1);
    MMAQ(1, 1, b1);
    MMAQ(1, 0, b0);
    __builtin_amdgcn_s_setprio(0);
  }

  // ---- epilogue ----
  int coln[2][2];
#pragma unroll
  for (int nh = 0; nh < 2; ++nh)
#pragma unroll
    for (int j = 0; j < 2; ++j) coln[nh][j] = n0 + nh * 128 + wn32 + j * 16 + l15;

  if constexpr (MODE == 0) {
    // fused scorer: s_partial[row] = sum over this block's 256 cols of relu(h)*w2
    float bias[2][2], w2v[2][2];
#pragma unroll
    for (int nh = 0; nh < 2; ++nh)
#pragma unroll
      for (int j = 0; j < 2; ++j) {
        bias[nh][j] = e0[(c << 10) + coln[nh][j]];
        w2v[nh][j]  = e1[(c << 10) + coln[nh][j]];
      }
    float* partL = (float*)&sA[0][0];  // final tile used buf 1 -> sA[0] free
#pragma unroll
    for (int mh = 0; mh < 2; ++mh)
#pragma unroll
      for (int i = 0; i < 4; ++i)
#pragma unroll
        for (int rr = 0; rr < 4; ++rr) {
          float s = 0.f;
#pragma unroll
          for (int nh = 0; nh < 2; ++nh)
#pragma unroll
            for (int j = 0; j < 2; ++j) {
              float v = fmaxf(acc[mh * 4 + i][nh * 2 + j][rr] + bias[nh][j], 0.f);
              s += v * w2v[nh][j];
            }
          s += __shfl_xor(s, 1); s += __shfl_xor(s, 2);
          s += __shfl_xor(s, 4); s += __shfl_xor(s, 8);
          if (l15 == 0) partL[wid * 128 + mh * 64 + i * 16 + (l4 << 2) + rr] = s;
        }
    __syncthreads();
    if (tid < 256) {
      const int r = tid;
      const int mh_ = r >> 7, wmr = (r >> 6) & 1, low = r & 63;
      float s2 = 0.f;
#pragma unroll
      for (int wn2 = 0; wn2 < 4; ++wn2) s2 += partL[(wmr * 4 + wn2) * 128 + mh_ * 64 + low];
      ofl[(((size_t)(bx << 6) + c) << 11) + m0 + r] = s2;
    }
  } else if constexpr (MODE == 1) {
    // in-epilogue sigmoid: cp for this block's 256 rows (e2 = spart)
    float* cpL = (float*)&sA[0][0];
    if (tid < 256) {
      const int b = m0 + tid;
      float s = p.b2[c];
#pragma unroll
      for (int q = 0; q < 4; ++q) s += e2[(((size_t)(q << 6) + c) << 11) + b];
      float pv = 1.f / (1.f + expf(-s));
      cpL[tid] = pv;
      if (bx == 0) {
        p.pred[((size_t)b << 6) + c] = pv;
        p.e1024[(c << 11) + b] =
            fmaxf(p.presum[(c << 11) + b] + pv * p.w2l[c] + p.bl1024[c], 0.f);
      }
    }
    __syncthreads();
    float wl4[2][2], bb4[2][2];
#pragma unroll
    for (int nh = 0; nh < 2; ++nh)
#pragma unroll
      for (int j = 0; j < 2; ++j) {
        wl4[nh][j] = e0[(c << 10) + coln[nh][j]];
        bb4[nh][j] = e1[(c << 10) + coln[nh][j]];
      }
#pragma unroll
    for (int mh = 0; mh < 2; ++mh)
#pragma unroll
      for (int i = 0; i < 4; ++i)
#pragma unroll
        for (int rr = 0; rr < 4; ++rr) {
          const int rl = mh * 128 + wm64 + i * 16 + (l4 << 2) + rr;
          const int row = m0 + rl;  // = b
          const float cp = cpL[rl];
          unsigned short* orow = obf + (((size_t)(c << 11) + row) << 10);
#pragma unroll
          for (int nh = 0; nh < 2; ++nh)
#pragma unroll
            for (int j = 0; j < 2; ++j) {
              float v = acc[mh * 4 + i][nh * 2 + j][rr] + cp * wl4[nh][j] + bb4[nh][j];
              orow[coln[nh][j]] = f2bf(fmaxf(v, 0.f));
            }
        }
  } else {
    float bias[2][2], wh[2][2];
#pragma unroll
    for (int nh = 0; nh < 2; ++nh)
#pragma unroll
      for (int j = 0; j < 2; ++j) {
        bias[nh][j] = (nh == 0) ? e0[coln[0][j]] : e1[coln[1][j] - 128];
        wh[nh][j]   = e3[coln[nh][j]];
      }
#pragma unroll
    for (int mh = 0; mh < 2; ++mh)
#pragma unroll
      for (int i = 0; i < 4; ++i)
#pragma unroll
        for (int rr = 0; rr < 4; ++rr) {
          const int rid = m0 + mh * 128 + wm64 + i * 16 + (l4 << 2) + rr;  // c*B + b
          const int cc = rid >> 11, b = rid & 2047;
          const float ev = e2[rid];  // e1024[c][b]
          const size_t ib = (((size_t)b << 6) + cc) << 7;
#pragma unroll
          for (int j = 0; j < 2; ++j) {  // nh=0 -> mu & ce
            float v = acc[mh * 4 + i][j][rr] + bias[0][j] + ev * wh[0][j];
            ofl[OFF_MU + ib + coln[0][j]] = v;
            ofl[OFF_CE + ib + coln[0][j]] = v;
          }
#pragma unroll
          for (int j = 0; j < 2; ++j) {  // nh=1 -> logvar
            float v = acc[mh * 4 + i][2 + j][rr] + bias[1][j] + ev * wh[1][j];
            ofl[OFF_LV + ib + (coln[1][j] - 128)] = v;
          }
        }
  }
}

// ---------------- launcher ----------------

extern "C" void kernel_launch(void* const* d_in, const int* in_sizes, int n_in,
                              void* d_out, int out_size, void* d_ws, size_t ws_size,
                              hipStream_t stream) {
  const float* x   = (const float*)d_in[0];
  const float* W1  = (const float*)d_in[2];
  const float* b1  = (const float*)d_in[3];
  const float* w2  = (const float*)d_in[4];
  const float* b2  = (const float*)d_in[5];
  const float* Wl  = (const float*)d_in[6];
  const float* bl  = (const float*)d_in[7];
  const float* Wmu = (const float*)d_in[8];
  const float* bmu = (const float*)d_in[9];
  const float* Wlv = (const float*)d_in[10];
  const float* blv = (const float*)d_in[11];
  float* out = (float*)d_out;

  char* ws = (char*)d_ws;
  size_t off = 0;
  auto take = [&](size_t bytes) { char* r = ws + off; off += bytes; return r; };
  unsigned short* xb     = (unsigned short*)take(4194304);
  unsigned short* W1T    = (unsigned short*)take(134217728);
  unsigned short* WlT    = (unsigned short*)take(134217728);  // separate: written while W1T read
  float* wlastf          = (float*)take(262144);
  float* blpf            = (float*)take(262144);
  float* Wlcolf          = (float*)take(262144);
  float* w2l             = (float*)take(512);
  float* bl1024          = (float*)take(512);
  unsigned short* WheadT = (unsigned short*)take(524288);
  float* whead1024f      = (float*)take(1024);
  float* presum          = (float*)take(524288);
  float* spart           = (float*)take(2097152);
  float* e1024f          = (float*)take(524288);
  unsigned short* emb    = (unsigned short*)take(268435456);
  // total = 545,523,712 bytes (fits: rounds 4/6/8/9/10 ran this footprint)

  PX p;
  p.Wl = Wl; p.Wmu = Wmu; p.Wlv = Wlv; p.b2 = b2;
  p.w2l = w2l; p.bl1024 = bl1024; p.Wlcolf = Wlcolf;
  p.xb = xb; p.WlT = WlT; p.WheadT = WheadT;
  p.whead1024f = whead1024f; p.presum = presum; p.e1024 = e1024f; p.pred = out;

  prep1_k<<<4736, 512, 0, stream>>>(W1, x, Wl, bl, xb, W1T, wlastf, blpf, Wlcolf, w2l, bl1024);
  // gemm1 (2048 gemm blocks) + 6656 tail blocks (Wl transpose x4/block, Whead, colgemv)
  gemm8p_k<0, 1024><<<8704, 512, 0, stream>>>(xb, W1T, b1, w2, nullptr, nullptr,
                                              nullptr, spart, p);
  gemm8p_k<1, 1024><<<dim3(4, 8, 64), 512, 0, stream>>>(xb, WlT, wlastf, blpf, spart, nullptr,
                                                        emb, nullptr, p);
  gemm8p_k<2, 1024><<<dim3(1, 512, 1), 512, 0, stream>>>(emb, WheadT, bmu, blv, e1024f,
                                                         whead1024f, nullptr, out, p);
}

// Round 12
// 930.744 us; speedup vs baseline: 7.3498x; 1.0335x over previous
//
#include <hip/hip_runtime.h>
#include <hip/hip_bf16.h>
#include <cstdint>
#include <cstddef>

// output regions (f32 elements)
#define OFF_CE 131072ull                 // c_emb [B,C,E]
#define OFF_MU (131072ull + 16777216ull) // mu
#define OFF_LV (131072ull + 33554432ull) // logvar

using bf16x8 = __attribute__((ext_vector_type(8))) __bf16;
using s16x8  = __attribute__((ext_vector_type(8))) short;
using f32x4  = __attribute__((ext_vector_type(4))) float;

__device__ __forceinline__ unsigned short f2bf(float x) {
  unsigned u = __builtin_bit_cast(unsigned, x);
  return (unsigned short)((u + 0x7FFFu + ((u >> 16) & 1u)) >> 16);
}
__device__ __forceinline__ float bf2f(unsigned short h) {
  unsigned u = ((unsigned)h) << 16;
  return __builtin_bit_cast(float, u);
}
__device__ __forceinline__ void async16(const void* g, void* l) {
  __builtin_amdgcn_global_load_lds(
      (const __attribute__((address_space(1))) void*)g,
      (__attribute__((address_space(3))) void*)l, 16, 0, 0);
}
// 16B nontemporal load via ext_vector (builtin vector type accepted by the builtin)
__device__ __forceinline__ f32x4 nt_load4(const float* p4) {
  return __builtin_nontemporal_load((const f32x4*)p4);
}

// everything the gemm kernel's epilogues + tail blocks need
struct PX {
  const float *Wl, *Wmu, *Wlv, *b2, *w2l, *bl1024, *Wlcolf;
  const unsigned short *xb;
  unsigned short *WlT, *WheadT;
  float *whead1024f, *presum, *e1024, *pred;
};

// ---- 64x64 f32 tile -> bf16 transposed tile (per 256-thread group). t=[64][68] LDS ----
template <int ALIGNED, int NT>
__device__ __forceinline__ void tile_tr64(const float* __restrict__ src, int stride,
                                          unsigned short* __restrict__ dst, int t256,
                                          float (*t)[68]) {
#pragma unroll
  for (int i = 0; i < 4; ++i) {
    const int row = (t256 >> 4) + (i << 4);
    const int col4 = (t256 & 15) << 2;
    const float* sp = src + (size_t)row * stride + col4;
    f32x4 v;
    if constexpr (ALIGNED && NT) {
      v = nt_load4(sp);
    } else if constexpr (ALIGNED) {
      v = *(const f32x4*)sp;
    } else if constexpr (NT) {
      v.x = __builtin_nontemporal_load(sp);
      v.y = __builtin_nontemporal_load(sp + 1);
      v.z = __builtin_nontemporal_load(sp + 2);
      v.w = __builtin_nontemporal_load(sp + 3);
    } else {
      v.x = sp[0]; v.y = sp[1]; v.z = sp[2]; v.w = sp[3];
    }
    *(f32x4*)&t[row][col4] = v;
  }
  __syncthreads();
  const int n = t256 & 63;
#pragma unroll
  for (int pq = 0; pq < 2; ++pq) {
    const int k8 = ((t256 >> 6) << 3) + (pq << 5);
    unsigned short tmp[8];
#pragma unroll
    for (int j = 0; j < 8; ++j) tmp[j] = f2bf(t[k8 + j][n]);
    *(uint4*)(dst + (size_t)n * 1024 + k8) = *(uint4*)tmp;
  }
}

// ---------------- prep1: W1 transpose + x convert + Wl extracts ----------------
// NT reads throughout: prep1 streams its inputs once; keeping them OUT of L3
// leaves the outputs (W1T, xb) resident for gemm1's staging (L3-hit latency).
__global__ __launch_bounds__(256) void prep1_k(const float* __restrict__ W1,
                                               const float* __restrict__ x,
                                               const float* __restrict__ Wl,
                                               const float* __restrict__ bl,
                                               unsigned short* __restrict__ xb,
                                               unsigned short* __restrict__ W1T,
                                               float* __restrict__ wlastf,
                                               float* __restrict__ blpf,
                                               float* __restrict__ Wlcolf,
                                               float* __restrict__ w2l,
                                               float* __restrict__ bl1024) {
  __shared__ float t[64][68];
  const int bid = blockIdx.x;
  const int tid = threadIdx.x;
  if (bid < 16384) {
    const int c = bid >> 8, kt = (bid >> 4) & 15, nt = bid & 15;
    tile_tr64<1, 1>(W1 + ((size_t)c << 20) + ((size_t)(kt << 6) << 10) + (nt << 6), 1024,
                    W1T + ((size_t)c << 20) + ((size_t)(nt << 6) << 10) + (kt << 6), tid, t);
  } else if (bid < 17408) {
    const int idx = (bid - 16384) * 256 + tid;  // < 262144
    f32x4 a = nt_load4(x + (size_t)idx * 8);
    f32x4 b = nt_load4(x + (size_t)idx * 8 + 4);
    unsigned w0 = f2bf(a.x) | ((unsigned)f2bf(a.y) << 16);
    unsigned w1 = f2bf(a.z) | ((unsigned)f2bf(a.w) << 16);
    unsigned w2 = f2bf(b.x) | ((unsigned)f2bf(b.y) << 16);
    unsigned w3 = f2bf(b.z) | ((unsigned)f2bf(b.w) << 16);
    ((uint4*)xb)[idx] = make_uint4(w0, w1, w2, w3);
  } else {
    const int idx = (bid - 17408) * 256 + tid;  // < 65536
    const int c = idx >> 10, j = idx & 1023;
    const float* src = Wl + (size_t)c * 1050625;
    wlastf[idx] = __builtin_nontemporal_load(&src[(size_t)1024 * 1025 + j]);
    blpf[idx]   = bl[(size_t)c * 1025 + j];
    Wlcolf[idx] = __builtin_nontemporal_load(&src[(size_t)j * 1025 + 1024]);
    if (j == 0) {
      w2l[c]    = src[(size_t)1024 * 1025 + 1024];
      bl1024[c] = bl[(size_t)c * 1025 + 1024];
    }
  }
}

// ---------------- tail work hidden in gemm1's dispatch ----------------
// e < 4096: Wl transpose, 4 tiles/block pair-pipelined; [4096,4608): Whead;
// [4608,6656): colgemv. Transposes FIRST: they're the long pole and feed gemm2.
__device__ void tail_work(int e, int tid, char* lds, const PX& p) {
  if (e < 4096) {
    const int g = tid >> 8, t256 = tid & 255;
    const int tau0 = (e << 2) + (g << 1);  // tiles tau0, tau0+1 (of 16384)
    float (*tA)[68] = (float(*)[68])(lds + g * 34816);
    float (*tB)[68] = (float(*)[68])(lds + g * 34816 + 17408);
    const int c0 = tau0 >> 8, kt0 = (tau0 >> 4) & 15, nt0 = tau0 & 15;
    const int tau1 = tau0 + 1;
    const int c1 = tau1 >> 8, kt1 = (tau1 >> 4) & 15, nt1 = tau1 & 15;
    const float* srcA = p.Wl + (size_t)c0 * 1050625 + (size_t)(kt0 << 6) * 1025 + (nt0 << 6);
    const float* srcB = p.Wl + (size_t)c1 * 1050625 + (size_t)(kt1 << 6) * 1025 + (nt1 << 6);
    unsigned short* dstA = p.WlT + ((size_t)c0 << 20) + ((size_t)(nt0 << 6) << 10) + (kt0 << 6);
    unsigned short* dstB = p.WlT + ((size_t)c1 << 20) + ((size_t)(nt1 << 6) << 10) + (kt1 << 6);
    const int row = t256 >> 4;
    const int col4 = (t256 & 15) << 2;
    f32x4 vA[4], vB[4];
#pragma unroll
    for (int i = 0; i < 4; ++i) {
      const float* q = srcA + (size_t)(row + (i << 4)) * 1025 + col4;
      vA[i].x = __builtin_nontemporal_load(q);
      vA[i].y = __builtin_nontemporal_load(q + 1);
      vA[i].z = __builtin_nontemporal_load(q + 2);
      vA[i].w = __builtin_nontemporal_load(q + 3);
    }
#pragma unroll
    for (int i = 0; i < 4; ++i) {
      const float* q = srcB + (size_t)(row + (i << 4)) * 1025 + col4;
      vB[i].x = __builtin_nontemporal_load(q);
      vB[i].y = __builtin_nontemporal_load(q + 1);
      vB[i].z = __builtin_nontemporal_load(q + 2);
      vB[i].w = __builtin_nontemporal_load(q + 3);
    }
#pragma unroll
    for (int i = 0; i < 4; ++i) *(f32x4*)&tA[row + (i << 4)][col4] = vA[i];
    __syncthreads();
#pragma unroll
    for (int i = 0; i < 4; ++i) *(f32x4*)&tB[row + (i << 4)][col4] = vB[i];
    const int n = t256 & 63;
#pragma unroll
    for (int pq = 0; pq < 2; ++pq) {
      const int k8 = ((t256 >> 6) << 3) + (pq << 5);
      unsigned short tmp[8];
#pragma unroll
      for (int j = 0; j < 8; ++j) tmp[j] = f2bf(tA[k8 + j][n]);
      *(uint4*)(dstA + (size_t)n * 1024 + k8) = *(uint4*)tmp;
    }
    __syncthreads();
#pragma unroll
    for (int pq = 0; pq < 2; ++pq) {
      const int k8 = ((t256 >> 6) << 3) + (pq << 5);
      unsigned short tmp[8];
#pragma unroll
      for (int j = 0; j < 8; ++j) tmp[j] = f2bf(tB[k8 + j][n]);
      *(uint4*)(dstB + (size_t)n * 1024 + k8) = *(uint4*)tmp;
    }
    return;
  }
  if (e < 4608) {  // Whead convert
    const int we = e - 4096;
    const int idx = we * 512 + tid;  // < 262144
    const int rr = idx >> 10, k = idx & 1023;
    float v = (rr < 128) ? p.Wmu[(size_t)k * 128 + rr] : p.Wlv[(size_t)k * 128 + (rr - 128)];
    p.WheadT[idx] = f2bf(v);
    if (we == 0 && tid < 256)
      p.whead1024f[tid] = (tid < 128) ? p.Wmu[131072 + tid] : p.Wlv[131072 + (tid - 128)];
    return;
  }
  // colgemv: presum[c][b] = x_b . Wlcol[c]
  const int b = e - 4608;  // < 2048
  const int w = tid >> 6, lane = tid & 63;
  const unsigned short* xr = p.xb + ((size_t)b << 10) + lane * 16;
  s16x8 xv0 = *(const s16x8*)xr;
  s16x8 xv1 = *(const s16x8*)(xr + 8);
  float xf[16];
#pragma unroll
  for (int i = 0; i < 8; ++i) {
    xf[i] = bf2f((unsigned short)xv0[i]);
    xf[8 + i] = bf2f((unsigned short)xv1[i]);
  }
#pragma unroll
  for (int q = 0; q < 8; ++q) {
    const int c = (q << 3) + w;
    const float* wr = p.Wlcolf + (c << 10) + lane * 16;
    float s = 0.f;
#pragma unroll
    for (int q4 = 0; q4 < 4; ++q4) {
      f32x4 wv = *(const f32x4*)(wr + q4 * 4);
      s += xf[q4 * 4 + 0] * wv.x + xf[q4 * 4 + 1] * wv.y +
           xf[q4 * 4 + 2] * wv.z + xf[q4 * 4 + 3] * wv.w;
    }
#pragma unroll
    for (int off = 32; off; off >>= 1) s += __shfl_xor(s, off);
    if (lane == 0) p.presum[(c << 11) + b] = s;
  }
}

// ---------------- 256x256 8-phase MFMA GEMM (T1+T2+T3+T4+T5), BK=64 ----------------
// MODE 0: h-tile + fused scorer partials -> ofl=spart[4][C][B]  (+6656 tail blocks)
// MODE 1: emb = relu(acc + cp*wlast + blp), in-epilogue sigmoid -> obf [C][B][1024]
// MODE 2: mu/lv/ce = acc + bias + e1024*whead1024 -> d_out

#define BAR() __builtin_amdgcn_s_barrier()
#define LGKM0() do { asm volatile("s_waitcnt lgkmcnt(0)" ::: "memory"); \
                     __builtin_amdgcn_sched_barrier(0); } while (0)
#define VM4() asm volatile("s_waitcnt vmcnt(4)" ::: "memory")
#define VM0() asm volatile("s_waitcnt vmcnt(0)" ::: "memory")

#define STAGEA(h, tt, bidx) do { _Pragma("unroll") for (int q_ = 0; q_ < 2; ++q_) \
  async16(Asrc[q_] + ((size_t)(h) * 128) * K + (size_t)(tt) * 64, \
          &sA[bidx][(h) * 8192 + chnk[q_]]); } while (0)
#define STAGEB(h, tt, bidx) do { _Pragma("unroll") for (int q_ = 0; q_ < 2; ++q_) \
  async16(Bsrc[q_] + ((size_t)(h) * 128) * K + (size_t)(tt) * 64, \
          &sB[bidx][(h) * 8192 + chnk[q_]]); } while (0)

#define LOADA(mh, bidx) do { _Pragma("unroll") for (int i_ = 0; i_ < 4; ++i_) { \
  const int ro_ = ((mh) * 128 + wm64 + i_ * 16 + l15) << 6; \
  a[i_][0] = *(const bf16x8*)&sA[bidx][ro_ + ccx0]; \
  a[i_][1] = *(const bf16x8*)&sA[bidx][ro_ + ccx1]; } } while (0)

#define LOADB(nh, bb, bidx) do { _Pragma("unroll") for (int j_ = 0; j_ < 2; ++j_) { \
  const int ro_ = ((nh) * 128 + wn32 + j_ * 16 + l15) << 6; \
  bb[j_][0] = *(const bf16x8*)&sB[bidx][ro_ + ccx0]; \
  bb[j_][1] = *(const bf16x8*)&sB[bidx][ro_ + ccx1]; } } while (0)

#define MMAQ(mh, nh, bb) do { _Pragma("unroll") for (int i_ = 0; i_ < 4; ++i_) \
  _Pragma("unroll") for (int j_ = 0; j_ < 2; ++j_) { \
    acc[(mh)*4+i_][(nh)*2+j_] = __builtin_amdgcn_mfma_f32_16x16x32_bf16( \
        a[i_][0], bb[j_][0], acc[(mh)*4+i_][(nh)*2+j_], 0, 0, 0); \
    acc[(mh)*4+i_][(nh)*2+j_] = __builtin_amdgcn_mfma_f32_16x16x32_bf16( \
        a[i_][1], bb[j_][1], acc[(mh)*4+i_][(nh)*2+j_], 0, 0, 0); \
  } } while (0)

// one full K-tile (4 phases) with compile-time LDS buffer selection
#define KSTEP(t_, cb_, nb_) do { \
    LOADA(0, cb_); LOADB(0, b0, cb_); STAGEA(0, (t_) + 1, nb_); \
    BAR(); LGKM0(); \
    __builtin_amdgcn_s_setprio(1); MMAQ(0, 0, b0); __builtin_amdgcn_s_setprio(0); \
    VM4(); BAR(); \
    LOADB(1, b1, cb_); STAGEB(0, (t_) + 1, nb_); \
    BAR(); LGKM0(); \
    __builtin_amdgcn_s_setprio(1); MMAQ(0, 1, b1); __builtin_amdgcn_s_setprio(0); \
    VM4(); BAR(); \
    LOADA(1, cb_); STAGEB(1, (t_) + 1, nb_); \
    BAR(); LGKM0(); \
    __builtin_amdgcn_s_setprio(1); MMAQ(1, 1, b1); __builtin_amdgcn_s_setprio(0); \
    BAR(); \
    STAGEA(1, (t_) + 1, nb_); \
    BAR(); \
    __builtin_amdgcn_s_setprio(1); MMAQ(1, 0, b0); __builtin_amdgcn_s_setprio(0); \
    VM4(); BAR(); \
  } while (0)

template <int MODE, int K>
__global__ __launch_bounds__(512, 2) void gemm8p_k(
    const unsigned short* __restrict__ A, const unsigned short* __restrict__ BT,
    const float* __restrict__ e0, const float* __restrict__ e1,
    const float* __restrict__ e2, const float* __restrict__ e3,
    unsigned short* __restrict__ obf, float* __restrict__ ofl, PX p) {
  __shared__ unsigned short sA[2][16384];
  __shared__ unsigned short sB[2][16384];

  constexpr int GX = (MODE == 2) ? 1 : 4;
  constexpr int GY = (MODE == 2) ? 512 : 8;
  constexpr int NWG = GX * GY * ((MODE == 2) ? 1 : 64);

  const int tid = threadIdx.x;

  int rbid;
  if constexpr (MODE == 0) {
    const int bidR = blockIdx.x;
    if (bidR >= 2048) { tail_work(bidR - 2048, tid, (char*)&sA[0][0], p); return; }
    rbid = bidR;
  } else {
    rbid = blockIdx.x + GX * (blockIdx.y + GY * blockIdx.z);
  }

  const int lane = tid & 63;
  const int wid = tid >> 6;
  const int wm = wid >> 2, wn = wid & 3;
  const int l15 = lane & 15, l4 = lane >> 4;
  const int wm64 = wm << 6, wn32 = wn << 5;

  // T1: bijective XCD swizzle (NWG % 8 == 0 for all modes)
  const int bid = (rbid & 7) * (NWG >> 3) + (rbid >> 3);
  const int bx = bid % GX;
  const int by = (bid / GX) % GY;
  const int c = bid / (GX * GY);

  const int n0 = bx << 8;
  const int m0 = by << 8;

  const unsigned short* Ab = A;
  const unsigned short* Bb;
  if constexpr (MODE == 2) Bb = BT;
  else                     Bb = BT + ((size_t)c << 20);

  // staging geometry: slot s holds source 16B-chunk (row=s>>3, cc=(s&7)^(row&7))
  int rloc[2], csrc[2], chnk[2];
  const unsigned short* Asrc[2];
  const unsigned short* Bsrc[2];
#pragma unroll
  for (int q = 0; q < 2; ++q) {
    const int s = ((wid << 1) + q) * 64 + lane;
    rloc[q] = s >> 3;
    csrc[q] = ((s & 7) ^ ((s >> 3) & 7)) << 3;
    chnk[q] = ((wid << 1) + q) << 9;
    Asrc[q] = Ab + (size_t)(m0 + rloc[q]) * K + csrc[q];
    Bsrc[q] = Bb + (size_t)(n0 + rloc[q]) * K + csrc[q];
  }

  // swizzled ds_read col-chunk offsets (in ushorts)
  const int xorv = l15 & 7;
  const int ccx0 = (l4 ^ xorv) << 3;
  const int ccx1 = ((4 + l4) ^ xorv) << 3;

  f32x4 acc[8][4];
#pragma unroll
  for (int i = 0; i < 8; ++i)
#pragma unroll
    for (int j = 0; j < 4; ++j) acc[i][j] = (f32x4)(0.f);

  bf16x8 a[4][2], b0[2][2], b1[2][2];

  // K = 1024 -> 16 K-tiles; 15 pipelined + 1 drained final
  static_assert(K == 1024, "schedule assumes 16 K-tiles");

  // prologue: stage tile 0, drain, barrier
  STAGEA(0, 0, 0); STAGEB(0, 0, 0); STAGEB(1, 0, 0); STAGEA(1, 0, 0);
  VM0();
  BAR();

#pragma unroll 1
  for (int tt = 0; tt < 7; ++tt) {
    const int t0 = tt << 1;
    KSTEP(t0, 0, 1);
    KSTEP(t0 + 1, 1, 0);
  }
  KSTEP(14, 0, 1);

  // ---- final tile t=15 in buffer 1 (race-safe: full drain; no further staging) ----
  {
    VM0();
    BAR();
    LOADA(0, 1);
    LOADB(0, b0, 1);
    LGKM0();
    __builtin_amdgcn_s_setprio(1);
    MMAQ(0, 0, b0);
    __builtin_amdgcn_s_setprio(0);
    LOADB(1, b1, 1);
    LGKM0();
    __builtin_amdgcn_s_setprio(1);
    MMAQ(0, 1, b1);
    __builtin_amdgcn_s_setprio(0);
    LOADA(1, 1);
    LGKM0();
    __builtin_amdgcn_s_setprio(1);
    MMAQ(1, 1, b1);
    MMAQ(1, 0, b0);
    __builtin_amdgcn_s_setprio(0);
  }

  // ---- epilogue ----
  int coln[2][2];
#pragma unroll
  for (int nh = 0; nh < 2; ++nh)
#pragma unroll
    for (int j = 0; j < 2; ++j) coln[nh][j] = n0 + nh * 128 + wn32 + j * 16 + l15;

  if constexpr (MODE == 0) {
    // fused scorer: s_partial[row] = sum over this block's 256 cols of relu(h)*w2
    float bias[2][2], w2v[2][2];
#pragma unroll
    for (int nh = 0; nh < 2; ++nh)
#pragma unroll
      for (int j = 0; j < 2; ++j) {
        bias[nh][j] = e0[(c << 10) + coln[nh][j]];
        w2v[nh][j]  = e1[(c << 10) + coln[nh][j]];
      }
    float* partL = (float*)&sA[0][0];  // final tile used buf 1 -> sA[0] free
#pragma unroll
    for (int mh = 0; mh < 2; ++mh)
#pragma unroll
      for (int i = 0; i < 4; ++i)
#pragma unroll
        for (int rr = 0; rr < 4; ++rr) {
          float s = 0.f;
#pragma unroll
          for (int nh = 0; nh < 2; ++nh)
#pragma unroll
            for (int j = 0; j < 2; ++j) {
              float v = fmaxf(acc[mh * 4 + i][nh * 2 + j][rr] + bias[nh][j], 0.f);
              s += v * w2v[nh][j];
            }
          s += __shfl_xor(s, 1); s += __shfl_xor(s, 2);
          s += __shfl_xor(s, 4); s += __shfl_xor(s, 8);
          if (l15 == 0) partL[wid * 128 + mh * 64 + i * 16 + (l4 << 2) + rr] = s;
        }
    __syncthreads();
    if (tid < 256) {
      const int r = tid;
      const int mh_ = r >> 7, wmr = (r >> 6) & 1, low = r & 63;
      float s2 = 0.f;
#pragma unroll
      for (int wn2 = 0; wn2 < 4; ++wn2) s2 += partL[(wmr * 4 + wn2) * 128 + mh_ * 64 + low];
      ofl[(((size_t)(bx << 6) + c) << 11) + m0 + r] = s2;
    }
  } else if constexpr (MODE == 1) {
    // in-epilogue sigmoid: cp for this block's 256 rows (e2 = spart)
    float* cpL = (float*)&sA[0][0];
    if (tid < 256) {
      const int b = m0 + tid;
      float s = p.b2[c];
#pragma unroll
      for (int q = 0; q < 4; ++q) s += e2[(((size_t)(q << 6) + c) << 11) + b];
      float pv = 1.f / (1.f + expf(-s));
      cpL[tid] = pv;
      if (bx == 0) {
        p.pred[((size_t)b << 6) + c] = pv;
        p.e1024[(c << 11) + b] =
            fmaxf(p.presum[(c << 11) + b] + pv * p.w2l[c] + p.bl1024[c], 0.f);
      }
    }
    __syncthreads();
    float wl4[2][2], bb4[2][2];
#pragma unroll
    for (int nh = 0; nh < 2; ++nh)
#pragma unroll
      for (int j = 0; j < 2; ++j) {
        wl4[nh][j] = e0[(c << 10) + coln[nh][j]];
        bb4[nh][j] = e1[(c << 10) + coln[nh][j]];
      }
#pragma unroll
    for (int mh = 0; mh < 2; ++mh)
#pragma unroll
      for (int i = 0; i < 4; ++i)
#pragma unroll
        for (int rr = 0; rr < 4; ++rr) {
          const int rl = mh * 128 + wm64 + i * 16 + (l4 << 2) + rr;
          const int row = m0 + rl;  // = b
          const float cp = cpL[rl];
          unsigned short* orow = obf + (((size_t)(c << 11) + row) << 10);
#pragma unroll
          for (int nh = 0; nh < 2; ++nh)
#pragma unroll
            for (int j = 0; j < 2; ++j) {
              float v = acc[mh * 4 + i][nh * 2 + j][rr] + cp * wl4[nh][j] + bb4[nh][j];
              orow[coln[nh][j]] = f2bf(fmaxf(v, 0.f));
            }
        }
  } else {
    float bias[2][2], wh[2][2];
#pragma unroll
    for (int nh = 0; nh < 2; ++nh)
#pragma unroll
      for (int j = 0; j < 2; ++j) {
        bias[nh][j] = (nh == 0) ? e0[coln[0][j]] : e1[coln[1][j] - 128];
        wh[nh][j]   = e3[coln[nh][j]];
      }
#pragma unroll
    for (int mh = 0; mh < 2; ++mh)
#pragma unroll
      for (int i = 0; i < 4; ++i)
#pragma unroll
        for (int rr = 0; rr < 4; ++rr) {
          const int rid = m0 + mh * 128 + wm64 + i * 16 + (l4 << 2) + rr;  // c*B + b
          const int cc = rid >> 11, b = rid & 2047;
          const float ev = e2[rid];  // e1024[c][b]
          const size_t ib = (((size_t)b << 6) + cc) << 7;
#pragma unroll
          for (int j = 0; j < 2; ++j) {  // nh=0 -> mu & ce
            float v = acc[mh * 4 + i][j][rr] + bias[0][j] + ev * wh[0][j];
            ofl[OFF_MU + ib + coln[0][j]] = v;
            ofl[OFF_CE + ib + coln[0][j]] = v;
          }
#pragma unroll
          for (int j = 0; j < 2; ++j) {  // nh=1 -> logvar
            float v = acc[mh * 4 + i][2 + j][rr] + bias[1][j] + ev * wh[1][j];
            ofl[OFF_LV + ib + (coln[1][j] - 128)] = v;
          }
        }
  }
}

// ---------------- launcher ----------------

extern "C" void kernel_launch(void* const* d_in, const int* in_sizes, int n_in,
                              void* d_out, int out_size, void* d_ws, size_t ws_size,
                              hipStream_t stream) {
  const float* x   = (const float*)d_in[0];
  const float* W1  = (const float*)d_in[2];
  const float* b1  = (const float*)d_in[3];
  const float* w2  = (const float*)d_in[4];
  const float* b2  = (const float*)d_in[5];
  const float* Wl  = (const float*)d_in[6];
  const float* bl  = (const float*)d_in[7];
  const float* Wmu = (const float*)d_in[8];
  const float* bmu = (const float*)d_in[9];
  const float* Wlv = (const float*)d_in[10];
  const float* blv = (const float*)d_in[11];
  float* out = (float*)d_out;

  char* ws = (char*)d_ws;
  size_t off = 0;
  auto take = [&](size_t bytes) { char* r = ws + off; off += bytes; return r; };
  unsigned short* xb     = (unsigned short*)take(4194304);
  unsigned short* W1T    = (unsigned short*)take(134217728);
  unsigned short* WlT    = (unsigned short*)take(134217728);  // separate: written while W1T read
  float* wlastf          = (float*)take(262144);
  float* blpf            = (float*)take(262144);
  float* Wlcolf          = (float*)take(262144);
  float* w2l             = (float*)take(512);
  float* bl1024          = (float*)take(512);
  unsigned short* WheadT = (unsigned short*)take(524288);
  float* whead1024f      = (float*)take(1024);
  float* presum          = (float*)take(524288);
  float* spart           = (float*)take(2097152);
  float* e1024f          = (float*)take(524288);
  unsigned short* emb    = (unsigned short*)take(268435456);
  // total = 545,523,712 bytes (fits: rounds 4/6/8/9/10/11 ran this footprint)

  PX p;
  p.Wl = Wl; p.Wmu = Wmu; p.Wlv = Wlv; p.b2 = b2;
  p.w2l = w2l; p.bl1024 = bl1024; p.Wlcolf = Wlcolf;
  p.xb = xb; p.WlT = WlT; p.WheadT = WheadT;
  p.whead1024f = whead1024f; p.presum = presum; p.e1024 = e1024f; p.pred = out;

  prep1_k<<<17664, 256, 0, stream>>>(W1, x, Wl, bl, xb, W1T, wlastf, blpf, Wlcolf, w2l, bl1024);
  // gemm1 (2048 gemm blocks) + 6656 tail blocks (Wl transpose x4/block, Whead, colgemv)
  gemm8p_k<0, 1024><<<8704, 512, 0, stream>>>(xb, W1T, b1, w2, nullptr, nullptr,
                                              nullptr, spart, p);
  gemm8p_k<1, 1024><<<dim3(4, 8, 64), 512, 0, stream>>>(xb, WlT, wlastf, blpf, spart, nullptr,
                                                        emb, nullptr, p);
  gemm8p_k<2, 1024><<<dim3(1, 512, 1), 512, 0, stream>>>(emb, WheadT, bmu, blv, e1024f,
                                                         whead1024f, nullptr, out, p);
}